// Round 16
// baseline (88.842 us; speedup 1.0000x reference)
//
#include <hip/hip_runtime.h>
#include <math.h>

#define NP 128       // patches per side
#define NB 32        // batch (light dirs)

typedef float vf4 __attribute__((ext_vector_type(4)));  // native 16B vector

// ---------------------------------------------------------------------------
// 4 light-dirs per block: bid = bc*128 + ph (xcd = ph%8 as R15).
//  phase 1: threads 0..127: load patch (ph,t)'s weights ONCE, run the MLP for
//           4 b's in registers (h[4][8]) -> 4x384 colors in LDS.
//  phase 2: per j: hoisted v[3] from cl[j], 24 NT float4 stores (R13 writer).
// ---------------------------------------------------------------------------
__global__ __launch_bounds__(256) void fused_relight4(
    const float* __restrict__ ld,   // [32][2]
    const float* __restrict__ w1,   // [p][8][2]
    const float* __restrict__ b1,   // [p][8]
    const float* __restrict__ w2,   // [p][8][8]
    const float* __restrict__ b2,   // [p][8]
    const float* __restrict__ w3,   // [p][8][8]
    const float* __restrict__ b3,   // [p][8]
    const float* __restrict__ wo,   // [p][3][8]
    const float* __restrict__ bo,   // [p][3]
    float* __restrict__ out)        // [32][1024][1024][3] f32
{
    int bid = blockIdx.x;        // 0 .. 1023
    int bc = bid >> 7;           // b-chunk (4 lights)
    int ph = bid & 127;          // patch row -> xcd = ph % 8
    int t  = threadIdx.x;        // 0 .. 255

    __shared__ float cl[4][NP * 3];  // 4 x 384 floats

    if (t < NP) {
        int p = ph * NP + t;     // patch id

        float x0[4], x1[4];
#pragma unroll
        for (int j = 0; j < 4; ++j) {
            int b = bc * 4 + j;
            x0[j] = ld[2 * b + 0];
            x1[j] = ld[2 * b + 1];
        }

        float h[4][8], g[4][8];

        {   // layer 1: 2 -> 8 (each weight used 4x)
            const float* W  = w1 + (size_t)p * 16;
            const float* Bv = b1 + (size_t)p * 8;
#pragma unroll
            for (int o = 0; o < 8; ++o) {
                float wa = W[2 * o + 0], wb = W[2 * o + 1], bb = Bv[o];
#pragma unroll
                for (int j = 0; j < 4; ++j)
                    h[j][o] = fmaxf(0.f, fmaf(wa, x0[j], fmaf(wb, x1[j], bb)));
            }
        }
        {   // layer 2: 8 -> 8
            const float* W  = w2 + (size_t)p * 64;
            const float* Bv = b2 + (size_t)p * 8;
#pragma unroll
            for (int o = 0; o < 8; ++o) {
                float bb = Bv[o];
                float s0 = bb, s1 = bb, s2 = bb, s3 = bb;
#pragma unroll
                for (int i = 0; i < 8; ++i) {
                    float w = W[8 * o + i];
                    s0 = fmaf(w, h[0][i], s0);
                    s1 = fmaf(w, h[1][i], s1);
                    s2 = fmaf(w, h[2][i], s2);
                    s3 = fmaf(w, h[3][i], s3);
                }
                g[0][o] = fmaxf(0.f, s0);
                g[1][o] = fmaxf(0.f, s1);
                g[2][o] = fmaxf(0.f, s2);
                g[3][o] = fmaxf(0.f, s3);
            }
        }
        {   // layer 3: 8 -> 8
            const float* W  = w3 + (size_t)p * 64;
            const float* Bv = b3 + (size_t)p * 8;
#pragma unroll
            for (int o = 0; o < 8; ++o) {
                float bb = Bv[o];
                float s0 = bb, s1 = bb, s2 = bb, s3 = bb;
#pragma unroll
                for (int i = 0; i < 8; ++i) {
                    float w = W[8 * o + i];
                    s0 = fmaf(w, g[0][i], s0);
                    s1 = fmaf(w, g[1][i], s1);
                    s2 = fmaf(w, g[2][i], s2);
                    s3 = fmaf(w, g[3][i], s3);
                }
                h[0][o] = fmaxf(0.f, s0);
                h[1][o] = fmaxf(0.f, s1);
                h[2][o] = fmaxf(0.f, s2);
                h[3][o] = fmaxf(0.f, s3);
            }
        }
        {   // out layer: 8 -> 3, sigmoid -> LDS
            const float* W  = wo + (size_t)p * 24;
            const float* Bv = bo + (size_t)p * 3;
#pragma unroll
            for (int c = 0; c < 3; ++c) {
                float bb = Bv[c];
                float s0 = bb, s1 = bb, s2 = bb, s3 = bb;
#pragma unroll
                for (int i = 0; i < 8; ++i) {
                    float w = W[8 * c + i];
                    s0 = fmaf(w, h[0][i], s0);
                    s1 = fmaf(w, h[1][i], s1);
                    s2 = fmaf(w, h[2][i], s2);
                    s3 = fmaf(w, h[3][i], s3);
                }
                cl[0][t * 3 + c] = 1.f / (1.f + expf(-s0));
                cl[1][t * 3 + c] = 1.f / (1.f + expf(-s1));
                cl[2][t * 3 + c] = 1.f / (1.f + expf(-s2));
                cl[3][t * 3 + c] = 1.f / (1.f + expf(-s3));
            }
        }
    }
    __syncthreads();

    // Phase 2 (R13 proven writer, per light j).
#pragma unroll
    for (int j = 0; j < 4; ++j) {
        vf4 v[3];
#pragma unroll
        for (int k = 0; k < 3; ++k) {
            int ct = k * 256 + t;         // 0..767
            int pw = ct / 6;
            int s  = ct % 3;

            float c0 = cl[j][pw * 3 + 0];
            float c1 = cl[j][pw * 3 + 1];
            float c2 = cl[j][pw * 3 + 2];
            float ca = (s == 0) ? c0 : ((s == 1) ? c1 : c2);
            float cb = (s == 0) ? c1 : ((s == 1) ? c2 : c0);
            float cc = (s == 0) ? c2 : ((s == 1) ? c0 : c1);

            v[k].x = ca; v[k].y = cb; v[k].z = cc; v[k].w = ca;
        }

        int b = bc * 4 + j;
        vf4* op = (vf4*)out + (size_t)b * 786432 + (size_t)ph * 6144;
#pragma unroll
        for (int row = 0; row < 8; ++row) {
            __builtin_nontemporal_store(v[0], &op[row * 768 + t]);
            __builtin_nontemporal_store(v[1], &op[row * 768 + 256 + t]);
            __builtin_nontemporal_store(v[2], &op[row * 768 + 512 + t]);
        }
    }
}

extern "C" void kernel_launch(void* const* d_in, const int* in_sizes, int n_in,
                              void* d_out, int out_size, void* d_ws, size_t ws_size,
                              hipStream_t stream) {
    const float* ld = (const float*)d_in[0];
    const float* w1 = (const float*)d_in[1];
    const float* b1 = (const float*)d_in[2];
    const float* w2 = (const float*)d_in[3];
    const float* b2 = (const float*)d_in[4];
    const float* w3 = (const float*)d_in[5];
    const float* b3 = (const float*)d_in[6];
    const float* wo = (const float*)d_in[7];
    const float* bo = (const float*)d_in[8];

    float* out = (float*)d_out;

    fused_relight4<<<dim3((NB / 4) * NP), dim3(256), 0, stream>>>(
        ld, w1, b1, w2, b2, w3, b3, wo, bo, out);
}